// Round 3
// baseline (447.769 us; speedup 1.0000x reference)
//
#include <hip/hip_runtime.h>
#include <hip/hip_bf16.h>
#include <stdint.h>

#define DEVI __device__ __forceinline__

typedef __attribute__((ext_vector_type(8))) __bf16 bf16x8;
typedef __attribute__((ext_vector_type(4))) float  f32x4;

constexpr int BM = 128, BN = 128, BK = 64;

DEVI unsigned int pack2(float a, float b) {
  unsigned short ha = __builtin_bit_cast(unsigned short, __float2bfloat16(a));
  unsigned short hb = __builtin_bit_cast(unsigned short, __float2bfloat16(b));
  return (unsigned int)ha | ((unsigned int)hb << 16);
}

// ---------------------------------------------------------------------------
// fp32 -> bf16 conversion, float4 / 8B-store vectorized. n4 = elems/4.
// ---------------------------------------------------------------------------
__global__ __launch_bounds__(256) void k_cvt(const float* __restrict__ src,
                                             __hip_bfloat16* __restrict__ dst, int n4) {
  int i = blockIdx.x * 256 + threadIdx.x;
  if (i < n4) {
    float4 f = ((const float4*)src)[i];
    uint2 u;
    u.x = pack2(f.x, f.y);
    u.y = pack2(f.z, f.w);
    ((uint2*)dst)[i] = u;
  }
}

// ---------------------------------------------------------------------------
// Staging: global -> LDS via global_load_lds (16B/lane). LDS dst is the
// wave-uniform base; HW writes base + lane*16. A 16B-chunk XOR swizzle is
// applied on the GLOBAL column so later ds_read_b128 fragment reads spread
// across banks (2 lanes/16B col = free per m136).
// LDS element (row, k) lives at row*64 + ((k/8) ^ (row&7))*8 + k%8.
// ---------------------------------------------------------------------------
DEVI void stage_tile(const __hip_bfloat16* gbase, int ld, unsigned short* lds, int tid) {
#pragma unroll
  for (int j = 0; j < 4; ++j) {
    int g   = j * 256 + tid;      // this lane's 16B chunk index (1024 = 16KB tile)
    int row = g >> 3;             // 8 chunks per 64-elem row
    int cp  = g & 7;              // swizzled chunk column (LDS side)
    int c   = cp ^ (row & 7);     // real chunk column (global side)
    const __hip_bfloat16* src = gbase + (size_t)row * ld + c * 8;
    unsigned short* dst = lds + (size_t)(j * 256 + (tid & ~63)) * 8;  // wave-uniform
    __builtin_amdgcn_global_load_lds((__attribute__((address_space(1))) void*)(src),
                                     (__attribute__((address_space(3))) void*)(dst),
                                     16, 0, 0);
  }
}

DEVI bf16x8 read_frag(const unsigned short* lds, int row, int kcol) {
  int c  = kcol >> 3;
  int cp = c ^ (row & 7);
  return *(const bf16x8*)(lds + row * 64 + cp * 8);
}

// ---------------------------------------------------------------------------
// 128x128x(64*ktiles) bf16 MFMA core, gemm_bt: C[m,n] = sum_k A[m,k]*B[n,k].
// 256 threads = 4 waves in 2x2 grid, each wave owns 64x64 = 4x4 MFMA tiles.
// mfma_f32_16x16x32_bf16: A[m=lane&15][k=quad*8+j]; C/D col=lane&15,
// row=quad*4+reg (verified layouts, m89/m91).
// ---------------------------------------------------------------------------
DEVI void gemm_core(const __hip_bfloat16* A0, int lda,
                    const __hip_bfloat16* B0, int ldb,
                    int ktiles, f32x4 (&acc)[4][4]) {
  __shared__ unsigned short sA[BM * BK];
  __shared__ unsigned short sB[BN * BK];
  const int tid  = threadIdx.x;
  const int lane = tid & 63;
  const int wid  = tid >> 6;
  const int quad = lane >> 4;
  const int lr   = lane & 15;
  const int wm   = (wid >> 1) * 64;
  const int wn   = (wid & 1) * 64;
  const f32x4 Z = {0.f, 0.f, 0.f, 0.f};
#pragma unroll
  for (int i = 0; i < 4; ++i)
#pragma unroll
    for (int j = 0; j < 4; ++j) acc[i][j] = Z;

  for (int kt = 0; kt < ktiles; ++kt) {
    stage_tile(A0 + kt * BK, lda, sA, tid);
    stage_tile(B0 + kt * BK, ldb, sB, tid);
    __syncthreads();   // compiler drains vmcnt before s_barrier
#pragma unroll
    for (int ks = 0; ks < BK; ks += 32) {
      bf16x8 af[4], bfr[4];
#pragma unroll
      for (int t = 0; t < 4; ++t) af[t]  = read_frag(sA, wm + t * 16 + lr, ks + quad * 8);
#pragma unroll
      for (int t = 0; t < 4; ++t) bfr[t] = read_frag(sB, wn + t * 16 + lr, ks + quad * 8);
#pragma unroll
      for (int i = 0; i < 4; ++i)
#pragma unroll
        for (int j = 0; j < 4; ++j)
          acc[i][j] = __builtin_amdgcn_mfma_f32_16x16x32_bf16(af[i], bfr[j], acc[i][j], 0, 0, 0);
    }
    __syncthreads();
  }
}

// ---------------------------------------------------------------------------
// Projection: C[16384,1024] = X @ W^T + b (bf16 in, bf16 out; bias fp32).
// VT=false: row-major bf16 out. VT=true: per-batch transposed Vt[b][e][s].
// ---------------------------------------------------------------------------
template <bool VT>
__global__ __launch_bounds__(256, 2) void k_proj(const __hip_bfloat16* __restrict__ X,
                                                 const __hip_bfloat16* __restrict__ W,
                                                 const float* __restrict__ bias,
                                                 __hip_bfloat16* __restrict__ C) {
  const int m0 = blockIdx.y * BM;
  const int n0 = blockIdx.x * BN;
  f32x4 acc[4][4];
  gemm_core(X + (size_t)m0 * 1024, 1024, W + (size_t)n0 * 1024, 1024, 16, acc);

  const int tid = threadIdx.x, lane = tid & 63, wid = tid >> 6;
  const int quad = lane >> 4, lr = lane & 15;
  const int wm = (wid >> 1) * 64, wn = (wid & 1) * 64;
  float bv[4];
#pragma unroll
  for (int j = 0; j < 4; ++j) bv[j] = bias[n0 + wn + j * 16 + lr];

  if (!VT) {
#pragma unroll
    for (int i = 0; i < 4; ++i)
#pragma unroll
      for (int j = 0; j < 4; ++j) {
        int n = n0 + wn + j * 16 + lr;
#pragma unroll
        for (int r = 0; r < 4; ++r) {
          int m = m0 + wm + i * 16 + quad * 4 + r;
          C[(size_t)m * 1024 + n] = __float2bfloat16(acc[i][j][r] + bv[j]);
        }
      }
  } else {
    const int b = m0 >> 11;                       // 128-row blocks never straddle batches
    __hip_bfloat16* Cb = C + ((size_t)b << 21);   // b * 1024 * 2048
    const int sb = (m0 & 2047) + wm;
#pragma unroll
    for (int i = 0; i < 4; ++i)
#pragma unroll
      for (int j = 0; j < 4; ++j) {
        int n  = n0 + wn + j * 16 + lr;
        int s0 = sb + i * 16 + quad * 4;          // 4 consecutive s -> 8B store
        uint2 u;
        u.x = pack2(acc[i][j][0] + bv[j], acc[i][j][1] + bv[j]);
        u.y = pack2(acc[i][j][2] + bv[j], acc[i][j][3] + bv[j]);
        *(uint2*)(Cb + (size_t)n * 2048 + s0) = u;
      }
  }
}

// ---------------------------------------------------------------------------
// Scores: S[z,q,k] = (Q . K) / 32, fp16, lower-triangular blocks only.
// z = local batch within this group; global batch = b0 + z.
// ---------------------------------------------------------------------------
__global__ __launch_bounds__(256, 2) void k_scores(const __hip_bfloat16* __restrict__ Q,
                                                   const __hip_bfloat16* __restrict__ Kmat,
                                                   _Float16* __restrict__ S, int b0) {
  const int kt = blockIdx.x, qt = blockIdx.y, z = blockIdx.z;
  if (kt > qt) return;   // fully-masked block: softmax never reads these
  const int b = b0 + z;
  const int m0 = qt * BM, n0 = kt * BN;
  f32x4 acc[4][4];
  const __hip_bfloat16* A0 = Q    + ((size_t)b << 21) + (size_t)m0 * 1024;
  const __hip_bfloat16* B0 = Kmat + ((size_t)b << 21) + (size_t)n0 * 1024;
  gemm_core(A0, 1024, B0, 1024, 16, acc);

  _Float16* Sb = S + ((size_t)z << 22);
  const int tid = threadIdx.x, lane = tid & 63, wid = tid >> 6;
  const int quad = lane >> 4, lr = lane & 15;
  const int wm = (wid >> 1) * 64, wn = (wid & 1) * 64;
#pragma unroll
  for (int i = 0; i < 4; ++i)
#pragma unroll
    for (int j = 0; j < 4; ++j) {
      int n = n0 + wn + j * 16 + lr;
#pragma unroll
      for (int r = 0; r < 4; ++r) {
        int m = m0 + wm + i * 16 + quad * 4 + r;
        Sb[(size_t)m * 2048 + n] = (_Float16)(acc[i][j][r] * 0.03125f);
      }
    }
}

// ---------------------------------------------------------------------------
// Row softmax over k<=q, in-place: reads fp16 S row (4096B), writes bf16 P
// over the same bytes (stride stays 2048 elems). k>q written as 0 (matches
// exp(-1e9) underflow). Reads land in registers before the first barrier;
// writes happen after the second -> no aliasing hazard.
// ---------------------------------------------------------------------------
__global__ __launch_bounds__(256) void k_softmax(_Float16* __restrict__ S) {
  const int row = blockIdx.x;              // local row within group chunk
  const int q = row & 2047;
  _Float16* srow = S + ((size_t)row << 11);
  const int tid = threadIdx.x;
  const int nv = q + 1;
  float loc[8];
  float mx = -1e30f;
#pragma unroll
  for (int i = 0; i < 8; ++i) {
    int k = tid + (i << 8);
    float v = (k < nv) ? (float)srow[k] : -1e30f;   // never read above diagonal
    loc[i] = v;
    mx = fmaxf(mx, v);
  }
#pragma unroll
  for (int off = 32; off > 0; off >>= 1) mx = fmaxf(mx, __shfl_xor(mx, off));
  __shared__ float rmax[4], rsum[4];
  if ((tid & 63) == 0) rmax[tid >> 6] = mx;
  __syncthreads();
  mx = fmaxf(fmaxf(rmax[0], rmax[1]), fmaxf(rmax[2], rmax[3]));

  float e[8], s = 0.f;
#pragma unroll
  for (int i = 0; i < 8; ++i) { e[i] = __expf(loc[i] - mx); s += e[i]; }
#pragma unroll
  for (int off = 32; off > 0; off >>= 1) s += __shfl_xor(s, off);
  if ((tid & 63) == 0) rsum[tid >> 6] = s;
  __syncthreads();
  s = rsum[0] + rsum[1] + rsum[2] + rsum[3];
  const float inv = 1.0f / s;

  __hip_bfloat16* prow = (__hip_bfloat16*)srow;
#pragma unroll
  for (int i = 0; i < 8; ++i) {
    int k = tid + (i << 8);
    prow[k] = __float2bfloat16(e[i] * inv);
  }
}

// ---------------------------------------------------------------------------
// PV: out[b,q,e] = sum_s P[q,s] * Vt[e,s], fp32 output.
// P rows overlay S (lda=2048 bf16). k-loop truncated at q0+128.
// ---------------------------------------------------------------------------
__global__ __launch_bounds__(256, 2) void k_pv(const _Float16* __restrict__ Sbase,
                                               const __hip_bfloat16* __restrict__ Vt,
                                               float* __restrict__ out, int b0) {
  const int nt = blockIdx.x, qt = blockIdx.y, z = blockIdx.z;
  const int b = b0 + z;
  const int m0 = qt * BM, n0 = nt * BN;
  const __hip_bfloat16* P  = (const __hip_bfloat16*)(Sbase + ((size_t)z << 22));
  const __hip_bfloat16* A0 = P + (size_t)m0 * 2048;
  const __hip_bfloat16* B0 = Vt + ((size_t)b << 21) + (size_t)n0 * 2048;
  const int ktiles = m0 / BK + 2;   // covers s in [0, q0+128)
  f32x4 acc[4][4];
  gemm_core(A0, 2048, B0, 2048, ktiles, acc);

  float* Cb = out + ((size_t)b << 21);
  const int tid = threadIdx.x, lane = tid & 63, wid = tid >> 6;
  const int quad = lane >> 4, lr = lane & 15;
  const int wm = (wid >> 1) * 64, wn = (wid & 1) * 64;
#pragma unroll
  for (int i = 0; i < 4; ++i)
#pragma unroll
    for (int j = 0; j < 4; ++j) {
      int n = n0 + wn + j * 16 + lr;
#pragma unroll
      for (int r = 0; r < 4; ++r) {
        int m = m0 + wm + i * 16 + quad * 4 + r;
        Cb[(size_t)m * 1024 + n] = acc[i][j][r];
      }
    }
}

extern "C" void kernel_launch(void* const* d_in, const int* in_sizes, int n_in,
                              void* d_out, int out_size, void* d_ws, size_t ws_size,
                              hipStream_t stream) {
  const float* x  = (const float*)d_in[0];
  const float* Wq = (const float*)d_in[1];
  const float* bq = (const float*)d_in[2];
  const float* Wk = (const float*)d_in[3];
  const float* bk = (const float*)d_in[4];
  const float* Wv = (const float*)d_in[5];
  const float* bv = (const float*)d_in[6];
  float* out = (float*)d_out;

  // ws layout (134 MB total):
  //   [0, 32MB)        xb (bf16 x)  -- dead after projections; REUSED as S
  //   [32MB, 38MB)     Wqb | Wkb | Wvb (bf16 weights, 2MB each)
  //   [38MB, 70MB)     Q   (bf16)
  //   [70MB, 102MB)    K   (bf16)
  //   [102MB, 134MB)   Vt  (bf16, per-batch transposed)
  char* ws = (char*)d_ws;
  const size_t MB32 = (size_t)33554432;
  __hip_bfloat16* xb  = (__hip_bfloat16*)(ws);
  __hip_bfloat16* Wqb = (__hip_bfloat16*)(ws + MB32);
  __hip_bfloat16* Wkb = (__hip_bfloat16*)(ws + MB32 + 2097152);
  __hip_bfloat16* Wvb = (__hip_bfloat16*)(ws + MB32 + 4194304);
  __hip_bfloat16* Q   = (__hip_bfloat16*)(ws + MB32 + 6291456);
  __hip_bfloat16* Kp  = (__hip_bfloat16*)(ws + 2 * MB32 + 6291456);
  __hip_bfloat16* Vt  = (__hip_bfloat16*)(ws + 3 * MB32 + 6291456);
  _Float16*       S   = (_Float16*)(ws);          // overlays dead xb

  dim3 blk(256);
  // fp32 -> bf16 prepass
  k_cvt<<<dim3(16384), blk, 0, stream>>>(x,  xb,  4194304);
  k_cvt<<<dim3(1024),  blk, 0, stream>>>(Wq, Wqb, 262144);
  k_cvt<<<dim3(1024),  blk, 0, stream>>>(Wk, Wkb, 262144);
  k_cvt<<<dim3(1024),  blk, 0, stream>>>(Wv, Wvb, 262144);

  k_proj<false><<<dim3(8, 128), blk, 0, stream>>>(xb, Wqb, bq, Q);
  k_proj<false><<<dim3(8, 128), blk, 0, stream>>>(xb, Wkb, bk, Kp);
  k_proj<true ><<<dim3(8, 128), blk, 0, stream>>>(xb, Wvb, bv, Vt);

  const int G = 4;   // batches per S-chunk round; S = G*8MB = 32MB fits xb slot
  for (int b0 = 0; b0 < 8; b0 += G) {
    k_scores <<<dim3(16, 16, G), blk, 0, stream>>>(Q, Kp, S, b0);
    k_softmax<<<dim3(G * 2048),  blk, 0, stream>>>(S);
    k_pv     <<<dim3(8, 16, G),  blk, 0, stream>>>(S, Vt, out, b0);
  }
}

// Round 5
// 400.177 us; speedup vs baseline: 1.1189x; 1.1189x over previous
//
#include <hip/hip_runtime.h>
#include <hip/hip_bf16.h>
#include <stdint.h>
#include <math.h>

#define DEVI __device__ __forceinline__

typedef __attribute__((ext_vector_type(8))) __bf16    bf16x8;
typedef __attribute__((ext_vector_type(8))) _Float16  f16x8;
typedef __attribute__((ext_vector_type(4))) float     f32x4;

constexpr int BM = 128, BN = 128, BK = 64;

DEVI unsigned int pack2(float a, float b) {
  unsigned short ha = __builtin_bit_cast(unsigned short, __float2bfloat16(a));
  unsigned short hb = __builtin_bit_cast(unsigned short, __float2bfloat16(b));
  return (unsigned int)ha | ((unsigned int)hb << 16);
}

// ---------------------------------------------------------------------------
// fp32 -> bf16 conversion, float4 / 8B-store vectorized. n4 = elems/4.
// ---------------------------------------------------------------------------
__global__ __launch_bounds__(256) void k_cvt(const float* __restrict__ src,
                                             __hip_bfloat16* __restrict__ dst, int n4) {
  int i = blockIdx.x * 256 + threadIdx.x;
  if (i < n4) {
    float4 f = ((const float4*)src)[i];
    uint2 u;
    u.x = pack2(f.x, f.y);
    u.y = pack2(f.z, f.w);
    ((uint2*)dst)[i] = u;
  }
}

// ---------------------------------------------------------------------------
// Staging: global -> LDS via global_load_lds (16B/lane), wave-uniform LDS
// base. XOR swizzle applied on the GLOBAL column so later ds_read_b128
// fragment reads spread across banks (2 lanes/16B col = free per m136).
// LDS element (row, k) lives at row*64 + ((k/8) ^ (row&7))*8 + k%8.
// ---------------------------------------------------------------------------
DEVI void stage_tile(const __hip_bfloat16* gbase, int ld, unsigned short* lds, int tid) {
#pragma unroll
  for (int j = 0; j < 4; ++j) {
    int g   = j * 256 + tid;      // this lane's 16B chunk index (1024 = 16KB tile)
    int row = g >> 3;             // 8 chunks per 64-elem row
    int cp  = g & 7;              // swizzled chunk column (LDS side)
    int c   = cp ^ (row & 7);     // real chunk column (global side)
    const __hip_bfloat16* src = gbase + (size_t)row * ld + c * 8;
    unsigned short* dst = lds + (size_t)(j * 256 + (tid & ~63)) * 8;  // wave-uniform
    __builtin_amdgcn_global_load_lds((__attribute__((address_space(1))) void*)(src),
                                     (__attribute__((address_space(3))) void*)(dst),
                                     16, 0, 0);
  }
}

DEVI bf16x8 read_frag(const unsigned short* lds, int row, int kcol) {
  int c  = kcol >> 3;
  int cp = c ^ (row & 7);
  return *(const bf16x8*)(lds + row * 64 + cp * 8);
}

// ---------------------------------------------------------------------------
// 128x128x(64*ktiles) bf16 MFMA core, gemm_bt: C[m,n] = sum_k A[m,k]*B[n,k].
// 256 threads = 4 waves in 2x2 grid, each wave owns 64x64 = 4x4 MFMA tiles.
// mfma_f32_16x16x32_bf16: A[m=lane&15][k=quad*8+j]; C/D col=lane&15,
// row=quad*4+reg (verified layouts, m89/m91).
// ---------------------------------------------------------------------------
DEVI void gemm_core(const __hip_bfloat16* A0, int lda,
                    const __hip_bfloat16* B0, int ldb,
                    int ktiles, f32x4 (&acc)[4][4]) {
  __shared__ unsigned short sA[BM * BK];
  __shared__ unsigned short sB[BN * BK];
  const int tid  = threadIdx.x;
  const int lane = tid & 63;
  const int wid  = tid >> 6;
  const int quad = lane >> 4;
  const int lr   = lane & 15;
  const int wm   = (wid >> 1) * 64;
  const int wn   = (wid & 1) * 64;
  const f32x4 Z = {0.f, 0.f, 0.f, 0.f};
#pragma unroll
  for (int i = 0; i < 4; ++i)
#pragma unroll
    for (int j = 0; j < 4; ++j) acc[i][j] = Z;

  for (int kt = 0; kt < ktiles; ++kt) {
    stage_tile(A0 + kt * BK, lda, sA, tid);
    stage_tile(B0 + kt * BK, ldb, sB, tid);
    __syncthreads();
#pragma unroll
    for (int ks = 0; ks < BK; ks += 32) {
      bf16x8 af[4], bfr[4];
#pragma unroll
      for (int t = 0; t < 4; ++t) af[t]  = read_frag(sA, wm + t * 16 + lr, ks + quad * 8);
#pragma unroll
      for (int t = 0; t < 4; ++t) bfr[t] = read_frag(sB, wn + t * 16 + lr, ks + quad * 8);
#pragma unroll
      for (int i = 0; i < 4; ++i)
#pragma unroll
        for (int j = 0; j < 4; ++j)
          acc[i][j] = __builtin_amdgcn_mfma_f32_16x16x32_bf16(af[i], bfr[j], acc[i][j], 0, 0, 0);
    }
    __syncthreads();
  }
}

// ---------------------------------------------------------------------------
// Projection: C[16384,1024] = X @ W^T + b (bf16 in/out; bias fp32).
// 1-D grid, XCD-aware swizzle: XCD j (id%8==j under round-robin dispatch)
// owns m-tiles [16j,16j+16) for all n -> per-XCD X working set 4MB (vs 32MB
// unswizzled: the cause of the round-3 132MB FETCH_SIZE).
// VT=true stores per-batch transposed Vt[b][e][s].
// ---------------------------------------------------------------------------
template <bool VT>
__global__ __launch_bounds__(256, 2) void k_proj(const __hip_bfloat16* __restrict__ X,
                                                 const __hip_bfloat16* __restrict__ W,
                                                 const float* __restrict__ bias,
                                                 __hip_bfloat16* __restrict__ C) {
  const int id = blockIdx.x;
  const int mt = ((id & 7) << 4) | ((id >> 3) & 15);
  const int nt = id >> 7;
  const int m0 = mt * BM;
  const int n0 = nt * BN;
  f32x4 acc[4][4];
  gemm_core(X + (size_t)m0 * 1024, 1024, W + (size_t)n0 * 1024, 1024, 16, acc);

  const int tid = threadIdx.x, lane = tid & 63, wid = tid >> 6;
  const int quad = lane >> 4, lr = lane & 15;
  const int wm = (wid >> 1) * 64, wn = (wid & 1) * 64;
  float bv[4];
#pragma unroll
  for (int j = 0; j < 4; ++j) bv[j] = bias[n0 + wn + j * 16 + lr];

  if (!VT) {
#pragma unroll
    for (int i = 0; i < 4; ++i)
#pragma unroll
      for (int j = 0; j < 4; ++j) {
        int n = n0 + wn + j * 16 + lr;
#pragma unroll
        for (int r = 0; r < 4; ++r) {
          int m = m0 + wm + i * 16 + quad * 4 + r;
          C[(size_t)m * 1024 + n] = __float2bfloat16(acc[i][j][r] + bv[j]);
        }
      }
  } else {
    const int b = m0 >> 11;                       // 128-row blocks never straddle batches
    __hip_bfloat16* Cb = C + ((size_t)b << 21);   // b * 1024 * 2048
    const int sb = (m0 & 2047) + wm;
#pragma unroll
    for (int i = 0; i < 4; ++i)
#pragma unroll
      for (int j = 0; j < 4; ++j) {
        int n  = n0 + wn + j * 16 + lr;
        int s0 = sb + i * 16 + quad * 4;          // 4 consecutive s -> 8B store
        uint2 u;
        u.x = pack2(acc[i][j][0] + bv[j], acc[i][j][1] + bv[j]);
        u.y = pack2(acc[i][j][2] + bv[j], acc[i][j][3] + bv[j]);
        *(uint2*)(Cb + (size_t)n * 2048 + s0) = u;
      }
  }
}

// ---------------------------------------------------------------------------
// Scores: S[z,q,k] = (Q . K) / 32, fp16, lower-triangular tiles only.
// 1-D grid of G*136: z = id&3 (batch <-> XCD pair), triangular tile decode.
// S is a separate ws region (G=4 batches x 8MB) -- NO aliasing with d_out.
// ---------------------------------------------------------------------------
__global__ __launch_bounds__(256, 2) void k_scores(const __hip_bfloat16* __restrict__ Q,
                                                   const __hip_bfloat16* __restrict__ Kmat,
                                                   _Float16* __restrict__ S, int b0) {
  const int id = blockIdx.x;
  const int z = id & 3;
  const int b = b0 + z;
  const int i = id >> 2;
  int qt = (int)((sqrtf(8.f * (float)i + 1.f) - 1.f) * 0.5f);
  while ((qt + 1) * (qt + 2) / 2 <= i) ++qt;
  while (qt * (qt + 1) / 2 > i) --qt;
  const int kt = i - qt * (qt + 1) / 2;

  const int m0 = qt * BM, n0 = kt * BN;
  f32x4 acc[4][4];
  const __hip_bfloat16* A0 = Q    + ((size_t)b << 21) + (size_t)m0 * 1024;
  const __hip_bfloat16* B0 = Kmat + ((size_t)b << 21) + (size_t)n0 * 1024;
  gemm_core(A0, 1024, B0, 1024, 16, acc);

  _Float16* Sb = S + ((size_t)z << 22);
  const int tid = threadIdx.x, lane = tid & 63, wid = tid >> 6;
  const int quad = lane >> 4, lr = lane & 15;
  const int wm = (wid >> 1) * 64, wn = (wid & 1) * 64;
#pragma unroll
  for (int i2 = 0; i2 < 4; ++i2)
#pragma unroll
    for (int j = 0; j < 4; ++j) {
      int n = n0 + wn + j * 16 + lr;
#pragma unroll
      for (int r = 0; r < 4; ++r) {
        int m = m0 + wm + i2 * 16 + quad * 4 + r;
        Sb[(size_t)m * 2048 + n] = (_Float16)(acc[i2][j][r] * 0.03125f);
      }
    }
}

// ---------------------------------------------------------------------------
// Row softmax over k<=q, in-place, fully vectorized: one 16B fp16x8 load and
// one 16B bf16x8 store per thread (256 thr x 8 = 2048 row elems). k>q written
// as 0 (matches exp(-1e9) underflow). Values above the diagonal (garbage or
// 0xAA poison -- finite fp16 either way) are masked before the max.
// ---------------------------------------------------------------------------
__global__ __launch_bounds__(256) void k_softmax(_Float16* __restrict__ S) {
  const int row = blockIdx.x;              // G*2048 rows in this chunk
  const int q = row & 2047;
  _Float16* srow = S + ((size_t)row << 11);
  const int t = threadIdx.x;
  const int k0 = t << 3;

  f16x8 h = ((const f16x8*)srow)[t];
  float v[8];
  float mx = -1e30f;
#pragma unroll
  for (int i = 0; i < 8; ++i) {
    float f = (float)h[i];
    v[i] = (k0 + i <= q) ? f : -1e30f;
    mx = fmaxf(mx, v[i]);
  }
#pragma unroll
  for (int off = 32; off > 0; off >>= 1) mx = fmaxf(mx, __shfl_xor(mx, off));
  __shared__ float rmax[4], rsum[4];
  if ((t & 63) == 0) rmax[t >> 6] = mx;
  __syncthreads();
  mx = fmaxf(fmaxf(rmax[0], rmax[1]), fmaxf(rmax[2], rmax[3]));

  float e[8], s = 0.f;
#pragma unroll
  for (int i = 0; i < 8; ++i) { e[i] = __expf(v[i] - mx); s += e[i]; }
#pragma unroll
  for (int off = 32; off > 0; off >>= 1) s += __shfl_xor(s, off);
  if ((t & 63) == 0) rsum[t >> 6] = s;
  __syncthreads();
  s = rsum[0] + rsum[1] + rsum[2] + rsum[3];
  const float inv = 1.0f / s;

  bf16x8 o;
#pragma unroll
  for (int i = 0; i < 8; ++i) o[i] = (__bf16)(e[i] * inv);
  ((bf16x8*)srow)[t] = o;
}

// ---------------------------------------------------------------------------
// PV: out[b,q,e] = sum_s P[q,s] * Vt[e,s], fp32 out (direct to d_out; S is in
// ws so there is NO read/write aliasing -- the round-4 race is gone).
// 1-D grid G*128: z = id&3 (batch<->XCD pair), longest qt first (tail kill).
// k-loop truncated at (qt+1)*128 (P is zero above the diagonal).
// ---------------------------------------------------------------------------
__global__ __launch_bounds__(256, 2) void k_pv(const _Float16* __restrict__ Sbase,
                                               const __hip_bfloat16* __restrict__ Vt,
                                               float* __restrict__ out, int b0) {
  const int id = blockIdx.x;
  const int z = id & 3;
  const int b = b0 + z;
  const int r2 = id >> 2;          // 0..127
  const int nt = r2 & 7;
  const int qt = 15 - (r2 >> 3);   // longest-running blocks dispatch first
  const int m0 = qt * BM, n0 = nt * BN;
  const __hip_bfloat16* P  = (const __hip_bfloat16*)(Sbase + ((size_t)z << 22));
  const __hip_bfloat16* A0 = P + (size_t)m0 * 2048;
  const __hip_bfloat16* B0 = Vt + ((size_t)b << 21) + (size_t)n0 * 2048;
  const int ktiles = 2 * qt + 2;   // covers s in [0, (qt+1)*128)
  f32x4 acc[4][4];
  gemm_core(A0, 2048, B0, 2048, ktiles, acc);

  float* Cb = out + ((size_t)b << 21);
  const int tid = threadIdx.x, lane = tid & 63, wid = tid >> 6;
  const int quad = lane >> 4, lr = lane & 15;
  const int wm = (wid >> 1) * 64, wn = (wid & 1) * 64;
#pragma unroll
  for (int i = 0; i < 4; ++i)
#pragma unroll
    for (int j = 0; j < 4; ++j) {
      int n = n0 + wn + j * 16 + lr;
#pragma unroll
      for (int r = 0; r < 4; ++r) {
        int m = m0 + wm + i * 16 + quad * 4 + r;
        Cb[(size_t)m * 1024 + n] = acc[i][j][r];
      }
    }
}

extern "C" void kernel_launch(void* const* d_in, const int* in_sizes, int n_in,
                              void* d_out, int out_size, void* d_ws, size_t ws_size,
                              hipStream_t stream) {
  const float* x  = (const float*)d_in[0];
  const float* Wq = (const float*)d_in[1];
  const float* bq = (const float*)d_in[2];
  const float* Wk = (const float*)d_in[3];
  const float* bk = (const float*)d_in[4];
  const float* Wv = (const float*)d_in[5];
  const float* bv = (const float*)d_in[6];
  float* out = (float*)d_out;

  // ws layout (134 MB) -- identical to the round-3 PASSING layout:
  //   [0, 32MB)        xb (bf16 x)  -- dead after projections; REUSED as S
  //   [32MB, 38MB)     Wqb | Wkb | Wvb (bf16 weights, 2MB each)
  //   [38MB, 70MB)     Q   (bf16)
  //   [70MB, 102MB)    K   (bf16)
  //   [102MB, 134MB)   Vt  (bf16, per-batch transposed)
  char* ws = (char*)d_ws;
  const size_t MB32 = (size_t)33554432;
  __hip_bfloat16* xb  = (__hip_bfloat16*)(ws);
  __hip_bfloat16* Wqb = (__hip_bfloat16*)(ws + MB32);
  __hip_bfloat16* Wkb = (__hip_bfloat16*)(ws + MB32 + 2097152);
  __hip_bfloat16* Wvb = (__hip_bfloat16*)(ws + MB32 + 4194304);
  __hip_bfloat16* Q   = (__hip_bfloat16*)(ws + MB32 + 6291456);
  __hip_bfloat16* Kp  = (__hip_bfloat16*)(ws + 2 * MB32 + 6291456);
  __hip_bfloat16* Vt  = (__hip_bfloat16*)(ws + 3 * MB32 + 6291456);
  _Float16*       S   = (_Float16*)(ws);          // overlays dead xb, 32MB

  dim3 blk(256);
  // fp32 -> bf16 prepass
  k_cvt<<<dim3(16384), blk, 0, stream>>>(x,  xb,  4194304);
  k_cvt<<<dim3(1024),  blk, 0, stream>>>(Wq, Wqb, 262144);
  k_cvt<<<dim3(1024),  blk, 0, stream>>>(Wk, Wkb, 262144);
  k_cvt<<<dim3(1024),  blk, 0, stream>>>(Wv, Wvb, 262144);

  k_proj<false><<<dim3(1024), blk, 0, stream>>>(xb, Wqb, bq, Q);
  k_proj<false><<<dim3(1024), blk, 0, stream>>>(xb, Wkb, bk, Kp);
  k_proj<true ><<<dim3(1024), blk, 0, stream>>>(xb, Wvb, bv, Vt);

  const int G = 4;   // batches per round; S = G*8MB = 32MB fits the xb slot
  for (int b0 = 0; b0 < 8; b0 += G) {
    k_scores <<<dim3(G * 136),  blk, 0, stream>>>(Q, Kp, S, b0);
    k_softmax<<<dim3(G * 2048), blk, 0, stream>>>(S);
    k_pv     <<<dim3(G * 128),  blk, 0, stream>>>(S, Vt, out, b0);
  }
}

// Round 6
// 369.926 us; speedup vs baseline: 1.2104x; 1.0818x over previous
//
#include <hip/hip_runtime.h>
#include <hip/hip_bf16.h>
#include <stdint.h>
#include <math.h>

#define DEVI __device__ __forceinline__

typedef __attribute__((ext_vector_type(8))) __bf16    bf16x8;
typedef __attribute__((ext_vector_type(8))) _Float16  f16x8;
typedef __attribute__((ext_vector_type(4))) float     f32x4;

constexpr int BM = 128, BN = 128, BK = 64;

DEVI unsigned int pack2(float a, float b) {
  unsigned short ha = __builtin_bit_cast(unsigned short, __float2bfloat16(a));
  unsigned short hb = __builtin_bit_cast(unsigned short, __float2bfloat16(b));
  return (unsigned int)ha | ((unsigned int)hb << 16);
}

// ---------------------------------------------------------------------------
// Merged fp32 -> bf16 conversion for x, Wq, Wk, Wv in ONE launch.
// i < 4194304 -> x; then 3 x 262144 (=2^18) float4-groups for the weights.
// Grid is exact: 19456 * 256 = 4980736.
// ---------------------------------------------------------------------------
__global__ __launch_bounds__(256) void k_cvt_all(const float* __restrict__ x,
                                                 const float* __restrict__ Wq,
                                                 const float* __restrict__ Wk,
                                                 const float* __restrict__ Wv,
                                                 __hip_bfloat16* __restrict__ xb,
                                                 __hip_bfloat16* __restrict__ Wqb,
                                                 __hip_bfloat16* __restrict__ Wkb,
                                                 __hip_bfloat16* __restrict__ Wvb) {
  int i = blockIdx.x * 256 + threadIdx.x;
  const float* src;
  __hip_bfloat16* dst;
  int k;
  if (i < 4194304) {
    src = x; dst = xb; k = i;
  } else {
    int j = i - 4194304;
    int w = j >> 18;
    k = j & 262143;
    src = (w == 0) ? Wq : (w == 1) ? Wk : Wv;
    dst = (w == 0) ? Wqb : (w == 1) ? Wkb : Wvb;
  }
  float4 f = ((const float4*)src)[k];
  uint2 u;
  u.x = pack2(f.x, f.y);
  u.y = pack2(f.z, f.w);
  ((uint2*)dst)[k] = u;
}

// ---------------------------------------------------------------------------
// Staging: global -> LDS via global_load_lds (16B/lane), wave-uniform LDS
// base. XOR swizzle applied on the GLOBAL column so later ds_read_b128
// fragment reads spread across banks (2 lanes/16B col = free per m136).
// LDS element (row, k) lives at row*64 + ((k/8) ^ (row&7))*8 + k%8.
// ---------------------------------------------------------------------------
DEVI void stage_tile(const __hip_bfloat16* gbase, int ld, unsigned short* lds, int tid) {
#pragma unroll
  for (int j = 0; j < 4; ++j) {
    int g   = j * 256 + tid;      // this lane's 16B chunk index (1024 = 16KB tile)
    int row = g >> 3;             // 8 chunks per 64-elem row
    int cp  = g & 7;              // swizzled chunk column (LDS side)
    int c   = cp ^ (row & 7);     // real chunk column (global side)
    const __hip_bfloat16* src = gbase + (size_t)row * ld + c * 8;
    unsigned short* dst = lds + (size_t)(j * 256 + (tid & ~63)) * 8;  // wave-uniform
    __builtin_amdgcn_global_load_lds((__attribute__((address_space(1))) void*)(src),
                                     (__attribute__((address_space(3))) void*)(dst),
                                     16, 0, 0);
  }
}

DEVI bf16x8 read_frag(const unsigned short* lds, int row, int kcol) {
  int c  = kcol >> 3;
  int cp = c ^ (row & 7);
  return *(const bf16x8*)(lds + row * 64 + cp * 8);
}

// ---------------------------------------------------------------------------
// 128x128x(64*ktiles) bf16 MFMA core, gemm_bt: C[m,n] = sum_k A[m,k]*B[n,k].
// 256 threads = 4 waves in 2x2 grid, each wave owns 64x64 = 4x4 MFMA tiles.
// mfma_f32_16x16x32_bf16: A[m=lane&15][k=quad*8+j]; C/D col=lane&15,
// row=quad*4+reg (verified layouts, m89/m91).
// LDS 32KB/block -> 4 blocks/CU at __launch_bounds__(256,4); VGPR 60 << 128.
// ---------------------------------------------------------------------------
DEVI void gemm_core(const __hip_bfloat16* A0, int lda,
                    const __hip_bfloat16* B0, int ldb,
                    int ktiles, f32x4 (&acc)[4][4]) {
  __shared__ unsigned short sA[BM * BK];
  __shared__ unsigned short sB[BN * BK];
  const int tid  = threadIdx.x;
  const int lane = tid & 63;
  const int wid  = tid >> 6;
  const int quad = lane >> 4;
  const int lr   = lane & 15;
  const int wm   = (wid >> 1) * 64;
  const int wn   = (wid & 1) * 64;
  const f32x4 Z = {0.f, 0.f, 0.f, 0.f};
#pragma unroll
  for (int i = 0; i < 4; ++i)
#pragma unroll
    for (int j = 0; j < 4; ++j) acc[i][j] = Z;

  for (int kt = 0; kt < ktiles; ++kt) {
    stage_tile(A0 + kt * BK, lda, sA, tid);
    stage_tile(B0 + kt * BK, ldb, sB, tid);
    __syncthreads();
#pragma unroll
    for (int ks = 0; ks < BK; ks += 32) {
      bf16x8 af[4], bfr[4];
#pragma unroll
      for (int t = 0; t < 4; ++t) af[t]  = read_frag(sA, wm + t * 16 + lr, ks + quad * 8);
#pragma unroll
      for (int t = 0; t < 4; ++t) bfr[t] = read_frag(sB, wn + t * 16 + lr, ks + quad * 8);
#pragma unroll
      for (int i = 0; i < 4; ++i)
#pragma unroll
        for (int j = 0; j < 4; ++j)
          acc[i][j] = __builtin_amdgcn_mfma_f32_16x16x32_bf16(af[i], bfr[j], acc[i][j], 0, 0, 0);
    }
    __syncthreads();
  }
}

// ---------------------------------------------------------------------------
// Merged QKV projection: ONE launch, grid 3072. w = id>>10 selects Q/K/V;
// inner id' = id & 1023 keeps the XCD swizzle (id%8 == id'%8 since 1024%8==0):
// XCD j owns X rows [2048j, 2048j+2048) = 4MB = its L2 -> X is L2-resident
// for the w=1 and w=2 segments. V output stored per-batch transposed.
// ---------------------------------------------------------------------------
__global__ __launch_bounds__(256, 4) void k_proj_qkv(const __hip_bfloat16* __restrict__ X,
                                                     const __hip_bfloat16* __restrict__ Wq,
                                                     const __hip_bfloat16* __restrict__ Wk,
                                                     const __hip_bfloat16* __restrict__ Wv,
                                                     const float* __restrict__ bq,
                                                     const float* __restrict__ bk,
                                                     const float* __restrict__ bv,
                                                     __hip_bfloat16* __restrict__ Q,
                                                     __hip_bfloat16* __restrict__ Kp,
                                                     __hip_bfloat16* __restrict__ Vt) {
  const int id = blockIdx.x;
  const int w  = id >> 10;                    // 0=Q 1=K 2=V
  const int i2 = id & 1023;
  const int mt = ((i2 & 7) << 4) | ((i2 >> 3) & 15);
  const int nt = i2 >> 7;
  const int m0 = mt * BM;
  const int n0 = nt * BN;

  const __hip_bfloat16* W = (w == 0) ? Wq : (w == 1) ? Wk : Wv;
  const float* bias       = (w == 0) ? bq : (w == 1) ? bk : bv;

  f32x4 acc[4][4];
  gemm_core(X + (size_t)m0 * 1024, 1024, W + (size_t)n0 * 1024, 1024, 16, acc);

  const int tid = threadIdx.x, lane = tid & 63, wid = tid >> 6;
  const int quad = lane >> 4, lr = lane & 15;
  const int wm = (wid >> 1) * 64, wn = (wid & 1) * 64;
  float bvv[4];
#pragma unroll
  for (int j = 0; j < 4; ++j) bvv[j] = bias[n0 + wn + j * 16 + lr];

  if (w != 2) {
    __hip_bfloat16* C = (w == 0) ? Q : Kp;
#pragma unroll
    for (int i = 0; i < 4; ++i)
#pragma unroll
      for (int j = 0; j < 4; ++j) {
        int n = n0 + wn + j * 16 + lr;
#pragma unroll
        for (int r = 0; r < 4; ++r) {
          int m = m0 + wm + i * 16 + quad * 4 + r;
          C[(size_t)m * 1024 + n] = __float2bfloat16(acc[i][j][r] + bvv[j]);
        }
      }
  } else {
    const int b = m0 >> 11;                        // 128-row blocks never straddle batches
    __hip_bfloat16* Cb = Vt + ((size_t)b << 21);   // b * 1024 * 2048
    const int sb = (m0 & 2047) + wm;
#pragma unroll
    for (int i = 0; i < 4; ++i)
#pragma unroll
      for (int j = 0; j < 4; ++j) {
        int n  = n0 + wn + j * 16 + lr;
        int s0 = sb + i * 16 + quad * 4;           // 4 consecutive s -> 8B store
        uint2 u;
        u.x = pack2(acc[i][j][0] + bvv[j], acc[i][j][1] + bvv[j]);
        u.y = pack2(acc[i][j][2] + bvv[j], acc[i][j][3] + bvv[j]);
        *(uint2*)(Cb + (size_t)n * 2048 + s0) = u;
      }
  }
}

// ---------------------------------------------------------------------------
// Scores: S[z,q,k] = (Q . K) / 32, fp16, lower-triangular tiles only.
// 1-D grid of G*136: z = id&3 (batch <-> XCD pair), triangular tile decode.
// S is a separate ws region (G=4 batches x 8MB) -- NO aliasing with d_out.
// ---------------------------------------------------------------------------
__global__ __launch_bounds__(256, 4) void k_scores(const __hip_bfloat16* __restrict__ Q,
                                                   const __hip_bfloat16* __restrict__ Kmat,
                                                   _Float16* __restrict__ S, int b0) {
  const int id = blockIdx.x;
  const int z = id & 3;
  const int b = b0 + z;
  const int i = id >> 2;
  int qt = (int)((sqrtf(8.f * (float)i + 1.f) - 1.f) * 0.5f);
  while ((qt + 1) * (qt + 2) / 2 <= i) ++qt;
  while (qt * (qt + 1) / 2 > i) --qt;
  const int kt = i - qt * (qt + 1) / 2;

  const int m0 = qt * BM, n0 = kt * BN;
  f32x4 acc[4][4];
  const __hip_bfloat16* A0 = Q    + ((size_t)b << 21) + (size_t)m0 * 1024;
  const __hip_bfloat16* B0 = Kmat + ((size_t)b << 21) + (size_t)n0 * 1024;
  gemm_core(A0, 1024, B0, 1024, 16, acc);

  _Float16* Sb = S + ((size_t)z << 22);
  const int tid = threadIdx.x, lane = tid & 63, wid = tid >> 6;
  const int quad = lane >> 4, lr = lane & 15;
  const int wm = (wid >> 1) * 64, wn = (wid & 1) * 64;
#pragma unroll
  for (int i2 = 0; i2 < 4; ++i2)
#pragma unroll
    for (int j = 0; j < 4; ++j) {
      int n = n0 + wn + j * 16 + lr;
#pragma unroll
      for (int r = 0; r < 4; ++r) {
        int m = m0 + wm + i2 * 16 + quad * 4 + r;
        Sb[(size_t)m * 2048 + n] = (_Float16)(acc[i2][j][r] * 0.03125f);
      }
    }
}

// ---------------------------------------------------------------------------
// Row softmax over k<=q, in-place, fully vectorized: one 16B fp16x8 load and
// one 16B bf16x8 store per thread. k>q written as 0 (matches exp(-1e9)
// underflow). Garbage above the diagonal is masked before the max.
// ---------------------------------------------------------------------------
__global__ __launch_bounds__(256) void k_softmax(_Float16* __restrict__ S) {
  const int row = blockIdx.x;              // G*2048 rows in this chunk
  const int q = row & 2047;
  _Float16* srow = S + ((size_t)row << 11);
  const int t = threadIdx.x;
  const int k0 = t << 3;

  f16x8 h = ((const f16x8*)srow)[t];
  float v[8];
  float mx = -1e30f;
#pragma unroll
  for (int i = 0; i < 8; ++i) {
    float f = (float)h[i];
    v[i] = (k0 + i <= q) ? f : -1e30f;
    mx = fmaxf(mx, v[i]);
  }
#pragma unroll
  for (int off = 32; off > 0; off >>= 1) mx = fmaxf(mx, __shfl_xor(mx, off));
  __shared__ float rmax[4], rsum[4];
  if ((t & 63) == 0) rmax[t >> 6] = mx;
  __syncthreads();
  mx = fmaxf(fmaxf(rmax[0], rmax[1]), fmaxf(rmax[2], rmax[3]));

  float e[8], s = 0.f;
#pragma unroll
  for (int i = 0; i < 8; ++i) { e[i] = __expf(v[i] - mx); s += e[i]; }
#pragma unroll
  for (int off = 32; off > 0; off >>= 1) s += __shfl_xor(s, off);
  if ((t & 63) == 0) rsum[t >> 6] = s;
  __syncthreads();
  s = rsum[0] + rsum[1] + rsum[2] + rsum[3];
  const float inv = 1.0f / s;

  bf16x8 o;
#pragma unroll
  for (int i = 0; i < 8; ++i) o[i] = (__bf16)(e[i] * inv);
  ((bf16x8*)srow)[t] = o;
}

// ---------------------------------------------------------------------------
// PV: out[b,q,e] = sum_s P[q,s] * Vt[e,s], fp32 out (direct to d_out; S is in
// ws so there is NO read/write aliasing).
// 1-D grid G*128: z = id&3 (batch<->XCD pair), longest qt first (tail kill).
// k-loop truncated at (qt+1)*128 (P is zero above the diagonal).
// ---------------------------------------------------------------------------
__global__ __launch_bounds__(256, 4) void k_pv(const _Float16* __restrict__ Sbase,
                                               const __hip_bfloat16* __restrict__ Vt,
                                               float* __restrict__ out, int b0) {
  const int id = blockIdx.x;
  const int z = id & 3;
  const int b = b0 + z;
  const int r2 = id >> 2;          // 0..127
  const int nt = r2 & 7;
  const int qt = 15 - (r2 >> 3);   // longest-running blocks dispatch first
  const int m0 = qt * BM, n0 = nt * BN;
  const __hip_bfloat16* P  = (const __hip_bfloat16*)(Sbase + ((size_t)z << 22));
  const __hip_bfloat16* A0 = P + (size_t)m0 * 2048;
  const __hip_bfloat16* B0 = Vt + ((size_t)b << 21) + (size_t)n0 * 2048;
  const int ktiles = 2 * qt + 2;   // covers s in [0, (qt+1)*128)
  f32x4 acc[4][4];
  gemm_core(A0, 2048, B0, 2048, ktiles, acc);

  float* Cb = out + ((size_t)b << 21);
  const int tid = threadIdx.x, lane = tid & 63, wid = tid >> 6;
  const int quad = lane >> 4, lr = lane & 15;
  const int wm = (wid >> 1) * 64, wn = (wid & 1) * 64;
#pragma unroll
  for (int i = 0; i < 4; ++i)
#pragma unroll
    for (int j = 0; j < 4; ++j) {
      int n = n0 + wn + j * 16 + lr;
#pragma unroll
      for (int r = 0; r < 4; ++r) {
        int m = m0 + wm + i * 16 + quad * 4 + r;
        Cb[(size_t)m * 1024 + n] = acc[i][j][r];
      }
    }
}

extern "C" void kernel_launch(void* const* d_in, const int* in_sizes, int n_in,
                              void* d_out, int out_size, void* d_ws, size_t ws_size,
                              hipStream_t stream) {
  const float* x  = (const float*)d_in[0];
  const float* Wq = (const float*)d_in[1];
  const float* bq = (const float*)d_in[2];
  const float* Wk = (const float*)d_in[3];
  const float* bk = (const float*)d_in[4];
  const float* Wv = (const float*)d_in[5];
  const float* bv = (const float*)d_in[6];
  float* out = (float*)d_out;

  // ws layout (134 MB):
  //   [0, 32MB)        xb (bf16 x)  -- dead after projections; REUSED as S
  //   [32MB, 38MB)     Wqb | Wkb | Wvb (bf16 weights, 2MB each)
  //   [38MB, 70MB)     Q   (bf16)
  //   [70MB, 102MB)    K   (bf16)
  //   [102MB, 134MB)   Vt  (bf16, per-batch transposed)
  char* ws = (char*)d_ws;
  const size_t MB32 = (size_t)33554432;
  __hip_bfloat16* xb  = (__hip_bfloat16*)(ws);
  __hip_bfloat16* Wqb = (__hip_bfloat16*)(ws + MB32);
  __hip_bfloat16* Wkb = (__hip_bfloat16*)(ws + MB32 + 2097152);
  __hip_bfloat16* Wvb = (__hip_bfloat16*)(ws + MB32 + 4194304);
  __hip_bfloat16* Q   = (__hip_bfloat16*)(ws + MB32 + 6291456);
  __hip_bfloat16* Kp  = (__hip_bfloat16*)(ws + 2 * MB32 + 6291456);
  __hip_bfloat16* Vt  = (__hip_bfloat16*)(ws + 3 * MB32 + 6291456);
  _Float16*       S   = (_Float16*)(ws);          // overlays dead xb, 32MB

  dim3 blk(256);
  k_cvt_all<<<dim3(19456), blk, 0, stream>>>(x, Wq, Wk, Wv, xb, Wqb, Wkb, Wvb);
  k_proj_qkv<<<dim3(3072), blk, 0, stream>>>(xb, Wqb, Wkb, Wvb, bq, bk, bv, Q, Kp, Vt);

  const int G = 4;   // batches per round; S = G*8MB = 32MB fits the xb slot
  for (int b0 = 0; b0 < 8; b0 += G) {
    k_scores <<<dim3(G * 136),  blk, 0, stream>>>(Q, Kp, S, b0);
    k_softmax<<<dim3(G * 2048), blk, 0, stream>>>(S);
    k_pv     <<<dim3(G * 128),  blk, 0, stream>>>(S, Vt, out, b0);
  }
}

// Round 7
// 344.855 us; speedup vs baseline: 1.2984x; 1.0727x over previous
//
#include <hip/hip_runtime.h>
#include <hip/hip_bf16.h>
#include <stdint.h>
#include <math.h>

#define DEVI __device__ __forceinline__

typedef __attribute__((ext_vector_type(8))) __bf16    bf16x8;
typedef __attribute__((ext_vector_type(8))) _Float16  f16x8;
typedef __attribute__((ext_vector_type(4))) float     f32x4;

constexpr int BM = 128, BN = 128, BK = 64;

DEVI unsigned int pack2(float a, float b) {
  unsigned short ha = __builtin_bit_cast(unsigned short, __float2bfloat16(a));
  unsigned short hb = __builtin_bit_cast(unsigned short, __float2bfloat16(b));
  return (unsigned int)ha | ((unsigned int)hb << 16);
}

// ---------------------------------------------------------------------------
// Merged fp32 -> bf16 conversion for x, Wq, Wk, Wv in ONE launch.
// ---------------------------------------------------------------------------
__global__ __launch_bounds__(256) void k_cvt_all(const float* __restrict__ x,
                                                 const float* __restrict__ Wq,
                                                 const float* __restrict__ Wk,
                                                 const float* __restrict__ Wv,
                                                 __hip_bfloat16* __restrict__ xb,
                                                 __hip_bfloat16* __restrict__ Wqb,
                                                 __hip_bfloat16* __restrict__ Wkb,
                                                 __hip_bfloat16* __restrict__ Wvb) {
  int i = blockIdx.x * 256 + threadIdx.x;
  const float* src;
  __hip_bfloat16* dst;
  int k;
  if (i < 4194304) {
    src = x; dst = xb; k = i;
  } else {
    int j = i - 4194304;
    int w = j >> 18;
    k = j & 262143;
    src = (w == 0) ? Wq : (w == 1) ? Wk : Wv;
    dst = (w == 0) ? Wqb : (w == 1) ? Wkb : Wvb;
  }
  float4 f = ((const float4*)src)[k];
  uint2 u;
  u.x = pack2(f.x, f.y);
  u.y = pack2(f.z, f.w);
  ((uint2*)dst)[k] = u;
}

// ---------------------------------------------------------------------------
// Staging: global -> LDS via global_load_lds (16B/lane), wave-uniform LDS
// base. XOR swizzle on the GLOBAL column so ds_read_b128 fragment reads
// spread across banks. LDS (row,k) at row*64 + ((k/8)^(row&7))*8 + k%8.
// ---------------------------------------------------------------------------
DEVI void stage_tile(const __hip_bfloat16* gbase, int ld, unsigned short* lds, int tid) {
#pragma unroll
  for (int j = 0; j < 4; ++j) {
    int g   = j * 256 + tid;
    int row = g >> 3;
    int cp  = g & 7;
    int c   = cp ^ (row & 7);
    const __hip_bfloat16* src = gbase + (size_t)row * ld + c * 8;
    unsigned short* dst = lds + (size_t)(j * 256 + (tid & ~63)) * 8;  // wave-uniform
    __builtin_amdgcn_global_load_lds((__attribute__((address_space(1))) void*)(src),
                                     (__attribute__((address_space(3))) void*)(dst),
                                     16, 0, 0);
  }
}

DEVI bf16x8 read_frag(const unsigned short* lds, int row, int kcol) {
  int c  = kcol >> 3;
  int cp = c ^ (row & 7);
  return *(const bf16x8*)(lds + row * 64 + cp * 8);
}

// ---------------------------------------------------------------------------
// 128x128x(64*ktiles) bf16 MFMA core, gemm_bt. LDS buffers passed in so
// multiple inlined calls in one kernel SHARE one 32KB allocation.
// ---------------------------------------------------------------------------
DEVI void gemm_core(unsigned short* sA, unsigned short* sB,
                    const __hip_bfloat16* A0, int lda,
                    const __hip_bfloat16* B0, int ldb,
                    int ktiles, f32x4 (&acc)[4][4]) {
  const int tid  = threadIdx.x;
  const int lane = tid & 63;
  const int wid  = tid >> 6;
  const int quad = lane >> 4;
  const int lr   = lane & 15;
  const int wm   = (wid >> 1) * 64;
  const int wn   = (wid & 1) * 64;
  const f32x4 Z = {0.f, 0.f, 0.f, 0.f};
#pragma unroll
  for (int i = 0; i < 4; ++i)
#pragma unroll
    for (int j = 0; j < 4; ++j) acc[i][j] = Z;

  for (int kt = 0; kt < ktiles; ++kt) {
    stage_tile(A0 + kt * BK, lda, sA, tid);
    stage_tile(B0 + kt * BK, ldb, sB, tid);
    __syncthreads();
#pragma unroll
    for (int ks = 0; ks < BK; ks += 32) {
      bf16x8 af[4], bfr[4];
#pragma unroll
      for (int t = 0; t < 4; ++t) af[t]  = read_frag(sA, wm + t * 16 + lr, ks + quad * 8);
#pragma unroll
      for (int t = 0; t < 4; ++t) bfr[t] = read_frag(sB, wn + t * 16 + lr, ks + quad * 8);
#pragma unroll
      for (int i = 0; i < 4; ++i)
#pragma unroll
        for (int j = 0; j < 4; ++j)
          acc[i][j] = __builtin_amdgcn_mfma_f32_16x16x32_bf16(af[i], bfr[j], acc[i][j], 0, 0, 0);
    }
    __syncthreads();
  }
}

// ---------------------------------------------------------------------------
// Merged QKV projection (one launch, grid 3072). Inner XCD swizzle keeps a
// 4MB per-XCD X working set. V stored per-batch transposed Vt[b][e][s].
// ---------------------------------------------------------------------------
__global__ __launch_bounds__(256, 4) void k_proj_qkv(const __hip_bfloat16* __restrict__ X,
                                                     const __hip_bfloat16* __restrict__ Wq,
                                                     const __hip_bfloat16* __restrict__ Wk,
                                                     const __hip_bfloat16* __restrict__ Wv,
                                                     const float* __restrict__ bq,
                                                     const float* __restrict__ bk,
                                                     const float* __restrict__ bv,
                                                     __hip_bfloat16* __restrict__ Q,
                                                     __hip_bfloat16* __restrict__ Kp,
                                                     __hip_bfloat16* __restrict__ Vt) {
  __shared__ unsigned short sA[BM * BK];
  __shared__ unsigned short sB[BN * BK];
  const int id = blockIdx.x;
  const int w  = id >> 10;                    // 0=Q 1=K 2=V
  const int i2 = id & 1023;
  const int mt = ((i2 & 7) << 4) | ((i2 >> 3) & 15);
  const int nt = i2 >> 7;
  const int m0 = mt * BM;
  const int n0 = nt * BN;

  const __hip_bfloat16* W = (w == 0) ? Wq : (w == 1) ? Wk : Wv;
  const float* bias       = (w == 0) ? bq : (w == 1) ? bk : bv;

  f32x4 acc[4][4];
  gemm_core(sA, sB, X + (size_t)m0 * 1024, 1024, W + (size_t)n0 * 1024, 1024, 16, acc);

  const int tid = threadIdx.x, lane = tid & 63, wid = tid >> 6;
  const int quad = lane >> 4, lr = lane & 15;
  const int wm = (wid >> 1) * 64, wn = (wid & 1) * 64;
  float bvv[4];
#pragma unroll
  for (int j = 0; j < 4; ++j) bvv[j] = bias[n0 + wn + j * 16 + lr];

  if (w != 2) {
    __hip_bfloat16* C = (w == 0) ? Q : Kp;
#pragma unroll
    for (int i = 0; i < 4; ++i)
#pragma unroll
      for (int j = 0; j < 4; ++j) {
        int n = n0 + wn + j * 16 + lr;
#pragma unroll
        for (int r = 0; r < 4; ++r) {
          int m = m0 + wm + i * 16 + quad * 4 + r;
          C[(size_t)m * 1024 + n] = __float2bfloat16(acc[i][j][r] + bvv[j]);
        }
      }
  } else {
    const int b = m0 >> 11;
    __hip_bfloat16* Cb = Vt + ((size_t)b << 21);
    const int sb = (m0 & 2047) + wm;
#pragma unroll
    for (int i = 0; i < 4; ++i)
#pragma unroll
      for (int j = 0; j < 4; ++j) {
        int n  = n0 + wn + j * 16 + lr;
        int s0 = sb + i * 16 + quad * 4;
        uint2 u;
        u.x = pack2(acc[i][j][0] + bvv[j], acc[i][j][1] + bvv[j]);
        u.y = pack2(acc[i][j][2] + bvv[j], acc[i][j][3] + bvv[j]);
        *(uint2*)(Cb + (size_t)n * 2048 + s0) = u;
      }
  }
}

// ---------------------------------------------------------------------------
// Scores: S[z,q,k] = (Q.K)/32, fp16, lower-triangular tiles only.
// Grid G*136; z = id & zmask (batch <-> XCD), triangular tile decode.
// ---------------------------------------------------------------------------
__global__ __launch_bounds__(256, 4) void k_scores(const __hip_bfloat16* __restrict__ Q,
                                                   const __hip_bfloat16* __restrict__ Kmat,
                                                   _Float16* __restrict__ S,
                                                   int b0, int zmask, int zshift) {
  __shared__ unsigned short sA[BM * BK];
  __shared__ unsigned short sB[BN * BK];
  const int id = blockIdx.x;
  const int z = id & zmask;
  const int b = b0 + z;
  const int i = id >> zshift;
  int qt = (int)((sqrtf(8.f * (float)i + 1.f) - 1.f) * 0.5f);
  while ((qt + 1) * (qt + 2) / 2 <= i) ++qt;
  while (qt * (qt + 1) / 2 > i) --qt;
  const int kt = i - qt * (qt + 1) / 2;

  const int m0 = qt * BM, n0 = kt * BN;
  f32x4 acc[4][4];
  const __hip_bfloat16* A0 = Q    + ((size_t)b << 21) + (size_t)m0 * 1024;
  const __hip_bfloat16* B0 = Kmat + ((size_t)b << 21) + (size_t)n0 * 1024;
  gemm_core(sA, sB, A0, 1024, B0, 1024, 16, acc);

  _Float16* Sb = S + ((size_t)z << 22);
  const int tid = threadIdx.x, lane = tid & 63, wid = tid >> 6;
  const int quad = lane >> 4, lr = lane & 15;
  const int wm = (wid >> 1) * 64, wn = (wid & 1) * 64;
#pragma unroll
  for (int i2 = 0; i2 < 4; ++i2)
#pragma unroll
    for (int j = 0; j < 4; ++j) {
      int n = n0 + wn + j * 16 + lr;
#pragma unroll
      for (int r = 0; r < 4; ++r) {
        int m = m0 + wm + i2 * 16 + quad * 4 + r;
        Sb[(size_t)m * 2048 + n] = (_Float16)(acc[i2][j][r] * 0.03125f);
      }
    }
}

// ---------------------------------------------------------------------------
// Row softmax over k<=q, in-place: 16B fp16x8 load (skipped entirely above
// the diagonal) and one 16B bf16x8 store per thread. k>q written as 0.
// ---------------------------------------------------------------------------
__global__ __launch_bounds__(256) void k_softmax(_Float16* __restrict__ S) {
  const int row = blockIdx.x;
  const int q = row & 2047;
  _Float16* srow = S + ((size_t)row << 11);
  const int t = threadIdx.x;
  const int k0 = t << 3;

  float v[8];
  float mx = -1e30f;
  if (k0 <= q) {
    f16x8 h = ((const f16x8*)srow)[t];
#pragma unroll
    for (int i = 0; i < 8; ++i) {
      float f = (float)h[i];
      v[i] = (k0 + i <= q) ? f : -1e30f;
      mx = fmaxf(mx, v[i]);
    }
  } else {
#pragma unroll
    for (int i = 0; i < 8; ++i) v[i] = -1e30f;
  }
#pragma unroll
  for (int off = 32; off > 0; off >>= 1) mx = fmaxf(mx, __shfl_xor(mx, off));
  __shared__ float rmax[4], rsum[4];
  if ((t & 63) == 0) rmax[t >> 6] = mx;
  __syncthreads();
  mx = fmaxf(fmaxf(rmax[0], rmax[1]), fmaxf(rmax[2], rmax[3]));

  float e[8], s = 0.f;
#pragma unroll
  for (int i = 0; i < 8; ++i) { e[i] = __expf(v[i] - mx); s += e[i]; }
#pragma unroll
  for (int off = 32; off > 0; off >>= 1) s += __shfl_xor(s, off);
  if ((t & 63) == 0) rsum[t >> 6] = s;
  __syncthreads();
  s = rsum[0] + rsum[1] + rsum[2] + rsum[3];
  const float inv = 1.0f / s;

  bf16x8 o;
#pragma unroll
  for (int i = 0; i < 8; ++i) o[i] = (__bf16)(e[i] * inv);
  ((bf16x8*)srow)[t] = o;
}

// ---------------------------------------------------------------------------
// PV: out[b,q,e] = sum_s P[q,s]*Vt[e,s], fp32 out. Load-balanced pairing:
// each block computes (qt=15-p, nt) then (qt=p, nt) -> uniform 36 ktiles.
// Grid G*64; z = id & zmask (batch<->XCD).
// ---------------------------------------------------------------------------
DEVI void pv_one(unsigned short* sA, unsigned short* sB,
                 const __hip_bfloat16* P, const __hip_bfloat16* VtB,
                 float* Cb, int qt, int nt) {
  const int m0 = qt * BM, n0 = nt * BN;
  const int ktiles = 2 * qt + 2;   // covers s in [0, (qt+1)*128)
  f32x4 acc[4][4];
  gemm_core(sA, sB, P + (size_t)m0 * 2048, 2048, VtB + (size_t)n0 * 2048, 2048, ktiles, acc);

  const int tid = threadIdx.x, lane = tid & 63, wid = tid >> 6;
  const int quad = lane >> 4, lr = lane & 15;
  const int wm = (wid >> 1) * 64, wn = (wid & 1) * 64;
#pragma unroll
  for (int i = 0; i < 4; ++i)
#pragma unroll
    for (int j = 0; j < 4; ++j) {
      int n = n0 + wn + j * 16 + lr;
#pragma unroll
      for (int r = 0; r < 4; ++r) {
        int m = m0 + wm + i * 16 + quad * 4 + r;
        Cb[(size_t)m * 1024 + n] = acc[i][j][r];
      }
    }
}

__global__ __launch_bounds__(256, 4) void k_pv(const _Float16* __restrict__ Sbase,
                                               const __hip_bfloat16* __restrict__ Vt,
                                               float* __restrict__ out,
                                               int b0, int zmask, int zshift) {
  __shared__ unsigned short sA[BM * BK];
  __shared__ unsigned short sB[BN * BK];
  const int id = blockIdx.x;
  const int z = id & zmask;
  const int b = b0 + z;
  const int r2 = id >> zshift;     // 0..63
  const int nt = r2 & 7;
  const int p  = (r2 >> 3) & 7;
  const __hip_bfloat16* P   = (const __hip_bfloat16*)(Sbase + ((size_t)z << 22));
  const __hip_bfloat16* VtB = Vt + ((size_t)b << 21);
  float* Cb = out + ((size_t)b << 21);
  pv_one(sA, sB, P, VtB, Cb, 15 - p, nt);   // long tile first
  pv_one(sA, sB, P, VtB, Cb, p, nt);        // short tile second
}

extern "C" void kernel_launch(void* const* d_in, const int* in_sizes, int n_in,
                              void* d_out, int out_size, void* d_ws, size_t ws_size,
                              hipStream_t stream) {
  const float* x  = (const float*)d_in[0];
  const float* Wq = (const float*)d_in[1];
  const float* bq = (const float*)d_in[2];
  const float* Wk = (const float*)d_in[3];
  const float* bk = (const float*)d_in[4];
  const float* Wv = (const float*)d_in[5];
  const float* bv = (const float*)d_in[6];
  float* out = (float*)d_out;

  char* ws = (char*)d_ws;
  const size_t MB32 = (size_t)33554432;
  const size_t MB64 = (size_t)67108864;

  __hip_bfloat16 *xb, *Wqb, *Wkb, *Wvb, *Q, *Kp, *Vt;
  _Float16* S;
  int G;
  if (ws_size >= (size_t)174063616) {
    // Big layout (166 MiB): [S 64MB (xb overlays first 32MB)] [W 6MB] [Q][K][Vt]
    S   = (_Float16*)(ws);
    xb  = (__hip_bfloat16*)(ws);                   // dead before S is written
    Wqb = (__hip_bfloat16*)(ws + MB64);
    Wkb = (__hip_bfloat16*)(ws + MB64 + 2097152);
    Wvb = (__hip_bfloat16*)(ws + MB64 + 4194304);
    Q   = (__hip_bfloat16*)(ws + MB64 + 6291456);
    Kp  = (__hip_bfloat16*)(ws + MB64 + 6291456 + MB32);
    Vt  = (__hip_bfloat16*)(ws + MB64 + 6291456 + 2 * MB32);
    G = 8;
  } else {
    // Small layout (134 MiB, proven): [xb 32MB == S 32MB] [W 6MB] [Q][K][Vt]
    S   = (_Float16*)(ws);
    xb  = (__hip_bfloat16*)(ws);
    Wqb = (__hip_bfloat16*)(ws + MB32);
    Wkb = (__hip_bfloat16*)(ws + MB32 + 2097152);
    Wvb = (__hip_bfloat16*)(ws + MB32 + 4194304);
    Q   = (__hip_bfloat16*)(ws + MB32 + 6291456);
    Kp  = (__hip_bfloat16*)(ws + 2 * MB32 + 6291456);
    Vt  = (__hip_bfloat16*)(ws + 3 * MB32 + 6291456);
    G = 4;
  }
  const int zmask  = G - 1;
  const int zshift = (G == 8) ? 3 : 2;

  dim3 blk(256);
  k_cvt_all<<<dim3(19456), blk, 0, stream>>>(x, Wq, Wk, Wv, xb, Wqb, Wkb, Wvb);
  k_proj_qkv<<<dim3(3072), blk, 0, stream>>>(xb, Wqb, Wkb, Wvb, bq, bk, bv, Q, Kp, Vt);

  for (int b0 = 0; b0 < 8; b0 += G) {
    k_scores <<<dim3(G * 136),  blk, 0, stream>>>(Q, Kp, S, b0, zmask, zshift);
    k_softmax<<<dim3(G * 2048), blk, 0, stream>>>(S);
    k_pv     <<<dim3(G * 64),   blk, 0, stream>>>(S, Vt, out, b0, zmask, zshift);
  }
}